// Round 5
// baseline (1688.913 us; speedup 1.0000x reference)
//
#include <hip/hip_runtime.h>

// ---------------- CSR construction ----------------

__global__ void count_kernel(const int* __restrict__ dst, int* __restrict__ counts, int E) {
    int e = blockIdx.x * 256 + threadIdx.x;
    if (e < E) atomicAdd(&counts[dst[e]], 1);
}

__global__ void scan_local(const int* __restrict__ counts, int* __restrict__ rowptr,
                           int* __restrict__ bsums, float* __restrict__ dinv, int N) {
    __shared__ int sm[256];
    int t = threadIdx.x;
    int gid = blockIdx.x * 256 + t;
    int v = (gid < N) ? counts[gid] : 0;
    if (gid < N) dinv[gid] = rsqrtf((float)v + 1.0f);
    int x = v;
    sm[t] = x; __syncthreads();
    for (int off = 1; off < 256; off <<= 1) {
        int y = (t >= off) ? sm[t - off] : 0;
        __syncthreads();
        x += y; sm[t] = x; __syncthreads();
    }
    if (gid < N) rowptr[gid] = x - v;
    if (t == 255) bsums[blockIdx.x] = x;
}

__global__ void scan_bsums(int* bsums, int nb) {
    __shared__ int sm[512];
    int t = threadIdx.x;
    int v = (t < nb) ? bsums[t] : 0;
    int x = v;
    sm[t] = x; __syncthreads();
    for (int off = 1; off < 512; off <<= 1) {
        int y = (t >= off) ? sm[t - off] : 0;
        __syncthreads();
        x += y; sm[t] = x; __syncthreads();
    }
    if (t < nb) bsums[t] = x - v;
}

__global__ void scan_add(int* __restrict__ rowptr, const int* __restrict__ bsums, int N) {
    int gid = blockIdx.x * 256 + threadIdx.x;
    if (gid < N) rowptr[gid] += bsums[blockIdx.x];
}

__global__ void fill_kernel(const int* __restrict__ src, const int* __restrict__ dst,
                            const int* __restrict__ rowptr, int* __restrict__ fillc,
                            const float* __restrict__ dinv,
                            int* __restrict__ csr, float* __restrict__ csrw, int E) {
    int e = blockIdx.x * 256 + threadIdx.x;
    if (e < E) {
        int d = dst[e];
        int s = src[e];
        int pos = rowptr[d] + atomicAdd(&fillc[d], 1);
        csr[pos] = s;
        csrw[pos] = dinv[s];
    }
}

// Shared inner loop: acc(lane) = sum_j csrw[j] * M[csr[j]*64 + lane]  (+ self term)
// Batched 8 wide: 8 independent 256B row-gathers in flight per wave.
__device__ __forceinline__ float agg_row(const float* __restrict__ M,
                                         const int* __restrict__ csr,
                                         const float* __restrict__ csrw,
                                         int start, int cnt, float self, int lane) {
    float acc = self;
    int j = 0;
    for (; j + 8 <= cnt; j += 8) {
        const int*   cp = csr  + start + j;
        const float* wp = csrw + start + j;
        int   s0 = cp[0], s1 = cp[1], s2 = cp[2], s3 = cp[3];
        int   s4 = cp[4], s5 = cp[5], s6 = cp[6], s7 = cp[7];
        float q0 = wp[0], q1 = wp[1], q2 = wp[2], q3 = wp[3];
        float q4 = wp[4], q5 = wp[5], q6 = wp[6], q7 = wp[7];
        float g0 = M[(size_t)s0 * 64 + lane];
        float g1 = M[(size_t)s1 * 64 + lane];
        float g2 = M[(size_t)s2 * 64 + lane];
        float g3 = M[(size_t)s3 * 64 + lane];
        float g4 = M[(size_t)s4 * 64 + lane];
        float g5 = M[(size_t)s5 * 64 + lane];
        float g6 = M[(size_t)s6 * 64 + lane];
        float g7 = M[(size_t)s7 * 64 + lane];
        acc = fmaf(q0, g0, acc); acc = fmaf(q1, g1, acc);
        acc = fmaf(q2, g2, acc); acc = fmaf(q3, g3, acc);
        acc = fmaf(q4, g4, acc); acc = fmaf(q5, g5, acc);
        acc = fmaf(q6, g6, acc); acc = fmaf(q7, g7, acc);
    }
    for (; j < cnt; ++j)
        acc = fmaf(csrw[start + j], M[(size_t)csr[start + j] * 64 + lane], acc);
    return acc;
}

// ---------------- xw = X @ W : 4 rows/wave via LDS transpose; W in LDS ----------------
// NO per-lane weight arrays: a 64-float alloca is never promoted to VGPRs and
// goes to HBM-backed scratch (rounds 3/4: 1.2 GB write traffic, 64 VGPRs).

__global__ void __launch_bounds__(128, 4)
gemm64_kernel(const float* __restrict__ X, const float* __restrict__ W,
              float* __restrict__ out, int N) {
    __shared__ float Wl[64 * 64];
    __shared__ float hbuf[2][256];
    int tid = threadIdx.x;
    int lane = tid & 63;
    for (int i = tid; i < 4096; i += 128) Wl[i] = W[i];
    __syncthreads();
    int wi = __builtin_amdgcn_readfirstlane(tid >> 6);
    float* hb = &hbuf[wi][0];
    int g0 = blockIdx.x * 2 + wi;
    int ng = gridDim.x * 2;
    int NG = (N + 3) >> 2;
    for (int g = g0; g < NG; g += ng) {
        int v0 = g * 4;
        float x0 = (v0 + 0 < N) ? X[(size_t)(v0 + 0) * 64 + lane] : 0.f;
        float x1 = (v0 + 1 < N) ? X[(size_t)(v0 + 1) * 64 + lane] : 0.f;
        float x2 = (v0 + 2 < N) ? X[(size_t)(v0 + 2) * 64 + lane] : 0.f;
        float x3 = (v0 + 3 < N) ? X[(size_t)(v0 + 3) * 64 + lane] : 0.f;
        *(float4*)&hb[lane * 4] = make_float4(x0, x1, x2, x3);
        float y0 = 0.f, y1 = 0.f, y2 = 0.f, y3 = 0.f;
#pragma unroll
        for (int k = 0; k < 64; ++k) {
            float4 hk = *(const float4*)&hb[k * 4];   // broadcast (same addr, free)
            float w = Wl[k * 64 + lane];              // stride-1, 2-way alias (free)
            y0 = fmaf(hk.x, w, y0);
            y1 = fmaf(hk.y, w, y1);
            y2 = fmaf(hk.z, w, y2);
            y3 = fmaf(hk.w, w, y3);
        }
        if (v0 + 0 < N) out[(size_t)(v0 + 0) * 64 + lane] = y0;
        if (v0 + 1 < N) out[(size_t)(v0 + 1) * 64 + lane] = y1;
        if (v0 + 2 < N) out[(size_t)(v0 + 2) * 64 + lane] = y2;
        if (v0 + 3 < N) out[(size_t)(v0 + 3) * 64 + lane] = y3;
    }
}

// ---------------- layer1 agg fused with @W2:  Y = relu(agg(XW)+b1) @ W2 ----------------

__global__ void __launch_bounds__(128, 4)
agg_mm_kernel(const float* __restrict__ XW, const int* __restrict__ csr,
              const float* __restrict__ csrw,
              const int* __restrict__ rowptr, const int* __restrict__ counts,
              const float* __restrict__ dinv, const float* __restrict__ bias,
              const float* __restrict__ W2, float* __restrict__ Y, int N) {
    __shared__ float Wl[64 * 64];
    __shared__ float hbuf[2][256];
    int tid = threadIdx.x;
    int lane = tid & 63;
    for (int i = tid; i < 4096; i += 128) Wl[i] = W2[i];
    __syncthreads();
    int wi = __builtin_amdgcn_readfirstlane(tid >> 6);
    float bb = bias[lane];
    float* hb = &hbuf[wi][0];
    int g0 = blockIdx.x * 2 + wi;
    int ng = gridDim.x * 2;
    int NG = (N + 3) >> 2;
    for (int g = g0; g < NG; g += ng) {
        int v0 = g * 4;
        float h0 = 0.f, h1 = 0.f, h2 = 0.f, h3 = 0.f;
#pragma unroll
        for (int rr = 0; rr < 4; ++rr) {
            int v = v0 + rr;
            if (v < N) {
                int start = rowptr[v];
                int cnt = counts[v];
                float dv = dinv[v];
                float acc = agg_row(XW, csr, csrw, start, cnt,
                                    dv * XW[(size_t)v * 64 + lane], lane);
                float hv = fmaxf(fmaf(dv, acc, bb), 0.f);
                if (rr == 0) h0 = hv; else if (rr == 1) h1 = hv;
                else if (rr == 2) h2 = hv; else h3 = hv;
            }
        }
        *(float4*)&hb[lane * 4] = make_float4(h0, h1, h2, h3);
        float y0 = 0.f, y1 = 0.f, y2 = 0.f, y3 = 0.f;
#pragma unroll
        for (int k = 0; k < 64; ++k) {
            float4 hk = *(const float4*)&hb[k * 4];
            float w = Wl[k * 64 + lane];
            y0 = fmaf(hk.x, w, y0);
            y1 = fmaf(hk.y, w, y1);
            y2 = fmaf(hk.z, w, y2);
            y3 = fmaf(hk.w, w, y3);
        }
        if (v0 + 0 < N) Y[(size_t)(v0 + 0) * 64 + lane] = y0;
        if (v0 + 1 < N) Y[(size_t)(v0 + 1) * 64 + lane] = y1;
        if (v0 + 2 < N) Y[(size_t)(v0 + 2) * 64 + lane] = y2;
        if (v0 + 3 < N) Y[(size_t)(v0 + 3) * 64 + lane] = y3;
    }
}

// ------- layer2 agg fused with MLP head:  out = relu(relu(agg(Y)+b2)@dW1+db1)@dW2+db2 -------

__global__ void __launch_bounds__(128, 4)
agg_head_kernel(const float* __restrict__ Yin, const int* __restrict__ csr,
                const float* __restrict__ csrw,
                const int* __restrict__ rowptr, const int* __restrict__ counts,
                const float* __restrict__ dinv, const float* __restrict__ b2,
                const float* __restrict__ dW1, const float* __restrict__ db1,
                const float* __restrict__ dW2, const float* __restrict__ db2,
                float* __restrict__ out, int N) {
    __shared__ float D1[64 * 64];
    __shared__ float W2l[64 * 16];
    __shared__ float tbuf[2][256];
    int tid = threadIdx.x;
    int lane = tid & 63;
    for (int i = tid; i < 4096; i += 128) D1[i] = dW1[i];
    for (int i = tid; i < 1024; i += 128) W2l[i] = dW2[i];
    __syncthreads();
    int wi = __builtin_amdgcn_readfirstlane(tid >> 6);
    float bbl = b2[lane];
    float bb1 = db1[lane];
    int c = lane & 15, rr2 = lane >> 4;
    float ob = db2[c];
    float* tb = &tbuf[wi][0];
    int g0 = blockIdx.x * 2 + wi;
    int ng = gridDim.x * 2;
    int NG = (N + 3) >> 2;
    for (int g = g0; g < NG; g += ng) {
        int v0 = g * 4;
        float h0 = 0.f, h1 = 0.f, h2 = 0.f, h3 = 0.f;
#pragma unroll
        for (int rr = 0; rr < 4; ++rr) {
            int v = v0 + rr;
            if (v < N) {
                int start = rowptr[v];
                int cnt = counts[v];
                float dv = dinv[v];
                float acc = agg_row(Yin, csr, csrw, start, cnt,
                                    dv * Yin[(size_t)v * 64 + lane], lane);
                float hv = fmaxf(fmaf(dv, acc, bbl), 0.f);   // h2 = relu(agg + b2)
                if (rr == 0) h0 = hv; else if (rr == 1) h1 = hv;
                else if (rr == 2) h2 = hv; else h3 = hv;
            }
        }
        // d1 = relu(h2 @ dW1 + db1), 4 rows at once via LDS transpose
        *(float4*)&tb[lane * 4] = make_float4(h0, h1, h2, h3);
        float y0 = bb1, y1 = bb1, y2 = bb1, y3 = bb1;
#pragma unroll
        for (int k = 0; k < 64; ++k) {
            float4 hk = *(const float4*)&tb[k * 4];
            float w = D1[k * 64 + lane];
            y0 = fmaf(hk.x, w, y0);
            y1 = fmaf(hk.y, w, y1);
            y2 = fmaf(hk.z, w, y2);
            y3 = fmaf(hk.w, w, y3);
        }
        y0 = fmaxf(y0, 0.f); y1 = fmaxf(y1, 0.f);
        y2 = fmaxf(y2, 0.f); y3 = fmaxf(y3, 0.f);
        // out = d1 @ dW2 + db2 : lane -> (row=rr2 of 4, col=c of 16)
        *(float4*)&tb[lane * 4] = make_float4(y0, y1, y2, y3);
        float o = 0.f;
#pragma unroll
        for (int k = 0; k < 64; ++k)
            o = fmaf(tb[k * 4 + rr2], W2l[k * 16 + c], o);
        int orow = v0 + rr2;
        if (orow < N) out[(size_t)v0 * 16 + lane] = o + ob;
    }
}

// ---------------- launch ----------------

extern "C" void kernel_launch(void* const* d_in, const int* in_sizes, int n_in,
                              void* d_out, int out_size, void* d_ws, size_t ws_size,
                              hipStream_t stream) {
    const float* x   = (const float*)d_in[0];
    const int*   ei  = (const int*)d_in[1];
    const float* W1  = (const float*)d_in[2];
    const float* b1  = (const float*)d_in[3];
    const float* W2  = (const float*)d_in[4];
    const float* b2  = (const float*)d_in[5];
    const float* dW1 = (const float*)d_in[6];
    const float* db1 = (const float*)d_in[7];
    const float* dW2 = (const float*)d_in[8];
    const float* db2 = (const float*)d_in[9];
    float* out = (float*)d_out;

    int N = in_sizes[0] / 64;
    int E = in_sizes[1] / 2;
    const int* src = ei;
    const int* dst = ei + E;

    size_t off = 0;
    auto alloc = [&](size_t bytes) {
        void* p = (char*)d_ws + off;
        off += (bytes + 511) & ~(size_t)511;
        return p;
    };
    int*   counts = (int*)alloc((size_t)N * 4);
    int*   fillc  = (int*)alloc((size_t)N * 4);
    int*   rowptr = (int*)alloc((size_t)N * 4);
    int*   bsums  = (int*)alloc(512 * 4);
    int*   csr    = (int*)alloc((size_t)E * 4);
    float* csrw   = (float*)alloc((size_t)E * 4);
    float* dinv   = (float*)alloc((size_t)N * 4);
    float* xw     = (float*)alloc((size_t)N * 64 * 4);
    float* yw     = (float*)alloc((size_t)N * 64 * 4);

    hipMemsetAsync(counts, 0, (size_t)N * 4, stream);
    hipMemsetAsync(fillc, 0, (size_t)N * 4, stream);

    int nbN = (N + 255) / 256;
    int nbE = (E + 255) / 256;

    count_kernel<<<nbE, 256, 0, stream>>>(dst, counts, E);
    scan_local<<<nbN, 256, 0, stream>>>(counts, rowptr, bsums, dinv, N);
    scan_bsums<<<1, 512, 0, stream>>>(bsums, nbN);
    scan_add<<<nbN, 256, 0, stream>>>(rowptr, bsums, N);
    fill_kernel<<<nbE, 256, 0, stream>>>(src, dst, rowptr, fillc, dinv, csr, csrw, E);

    gemm64_kernel<<<4096, 128, 0, stream>>>(x, W1, xw, N);
    agg_mm_kernel<<<4096, 128, 0, stream>>>(xw, csr, csrw, rowptr, counts, dinv, b1, W2, yw, N);
    agg_head_kernel<<<4096, 128, 0, stream>>>(yw, csr, csrw, rowptr, counts, dinv, b2,
                                              dW1, db1, dW2, db2, out, N);
}

// Round 6
// 724.716 us; speedup vs baseline: 2.3304x; 2.3304x over previous
//
#include <hip/hip_runtime.h>

// ---------------- CSR construction ----------------

__global__ void count_kernel(const int* __restrict__ dst, int* __restrict__ counts, int E) {
    int e = blockIdx.x * 256 + threadIdx.x;
    if (e < E) atomicAdd(&counts[dst[e]], 1);
}

__global__ void scan_local(const int* __restrict__ counts, int* __restrict__ rowptr,
                           int* __restrict__ bsums, float* __restrict__ dinv, int N) {
    __shared__ int sm[256];
    int t = threadIdx.x;
    int gid = blockIdx.x * 256 + t;
    int v = (gid < N) ? counts[gid] : 0;
    if (gid < N) dinv[gid] = rsqrtf((float)v + 1.0f);
    int x = v;
    sm[t] = x; __syncthreads();
    for (int off = 1; off < 256; off <<= 1) {
        int y = (t >= off) ? sm[t - off] : 0;
        __syncthreads();
        x += y; sm[t] = x; __syncthreads();
    }
    if (gid < N) rowptr[gid] = x - v;
    if (t == 255) bsums[blockIdx.x] = x;
}

__global__ void scan_bsums(int* bsums, int nb) {
    __shared__ int sm[512];
    int t = threadIdx.x;
    int v = (t < nb) ? bsums[t] : 0;
    int x = v;
    sm[t] = x; __syncthreads();
    for (int off = 1; off < 512; off <<= 1) {
        int y = (t >= off) ? sm[t - off] : 0;
        __syncthreads();
        x += y; sm[t] = x; __syncthreads();
    }
    if (t < nb) bsums[t] = x - v;
}

__global__ void scan_add(int* __restrict__ rowptr, const int* __restrict__ bsums, int N) {
    int gid = blockIdx.x * 256 + threadIdx.x;
    if (gid < N) rowptr[gid] += bsums[blockIdx.x];
}

__global__ void fill_kernel(const int* __restrict__ src, const int* __restrict__ dst,
                            const int* __restrict__ rowptr, int* __restrict__ fillc,
                            const float* __restrict__ dinv,
                            int* __restrict__ csr, float* __restrict__ csrw, int E) {
    int e = blockIdx.x * 256 + threadIdx.x;
    if (e < E) {
        int d = dst[e];
        int s = src[e];
        int pos = rowptr[d] + atomicAdd(&fillc[d], 1);
        csr[pos] = s;
        csrw[pos] = dinv[s];
    }
}

// ---------------- xw = X @ W : R4 version (empirically fastest gemm) ----------------

__global__ void __launch_bounds__(128, 4)
gemm64_kernel(const float* __restrict__ X, const float* __restrict__ W,
              float* __restrict__ out, int N) {
    int tid = threadIdx.x;
    int lane = tid & 63;
    int wi = __builtin_amdgcn_readfirstlane(tid >> 6);
    float wc[64];
#pragma unroll
    for (int k = 0; k < 64; ++k) wc[k] = W[k * 64 + lane];
    int r0 = blockIdx.x * 2 + wi;
    int nw = gridDim.x * 2;
    for (int r = r0; r < N; r += nw) {
        const float* xr = X + (size_t)r * 64;   // wave-uniform row base
        float a0 = 0.f, a1 = 0.f;
#pragma unroll
        for (int k = 0; k < 64; k += 2) {
            a0 = fmaf(xr[k],     wc[k],     a0);
            a1 = fmaf(xr[k + 1], wc[k + 1], a1);
        }
        out[(size_t)r * 64 + lane] = a0 + a1;
    }
}

// ------- layer1 agg fused with @W2 (R2 shuffle-gather structure, csrw coalesced) -------

__global__ void agg_mm_kernel(const float* __restrict__ XW, const int* __restrict__ csr,
                              const float* __restrict__ csrw,
                              const int* __restrict__ rowptr, const int* __restrict__ counts,
                              const float* __restrict__ dinv, const float* __restrict__ bias,
                              const float* __restrict__ W2, float* __restrict__ Y, int N) {
    __shared__ float Wl[64 * 64];
    int tid = threadIdx.x;
    for (int i = tid; i < 4096; i += 256) Wl[i] = W2[i];
    __syncthreads();
    int lane = tid & 63, wave = tid >> 6;
    float bb = bias[lane];
    int v0 = blockIdx.x * 4 + wave;
    int stride = gridDim.x * 4;
    for (int v = v0; v < N; v += stride) {
        int start = rowptr[v], cnt = counts[v];
        float dv = dinv[v];
        float acc = dv * XW[(size_t)v * 64 + lane];
        for (int base = 0; base < cnt; base += 64) {
            int nb = min(64, cnt - base);
            int idx = 0; float ds = 0.f;
            if (lane < nb) {
                idx = csr[start + base + lane];     // coalesced
                ds  = csrw[start + base + lane];    // coalesced (was dinv[idx] gather in R2)
            }
            for (int j = 0; j < nb; ++j) {
                int s = __shfl(idx, j);             // indices stay register-resident:
                float d = __shfl(ds, j);            // gathers pipeline many-deep
                acc = fmaf(d, XW[(size_t)s * 64 + lane], acc);
            }
        }
        float h = fmaxf(fmaf(dv, acc, bb), 0.f);
        float y = 0.f;
#pragma unroll
        for (int k = 0; k < 64; ++k)
            y = fmaf(__shfl(h, k), Wl[k * 64 + lane], y);
        Y[(size_t)v * 64 + lane] = y;
    }
}

// ------- layer2 agg fused with MLP head (R2 structure, csrw coalesced) -------

__global__ void agg_head_kernel(const float* __restrict__ Yin, const int* __restrict__ csr,
                                const float* __restrict__ csrw,
                                const int* __restrict__ rowptr, const int* __restrict__ counts,
                                const float* __restrict__ dinv, const float* __restrict__ b2,
                                const float* __restrict__ dW1, const float* __restrict__ db1,
                                const float* __restrict__ dW2, const float* __restrict__ db2,
                                float* __restrict__ out, int N) {
    __shared__ float D1[64 * 64];
    int tid = threadIdx.x;
    for (int i = tid; i < 4096; i += 256) D1[i] = dW1[i];
    __syncthreads();
    int lane = tid & 63, wave = tid >> 6;
    int c = lane & 15, part = lane >> 4;
    float d2r[16];
#pragma unroll
    for (int kk = 0; kk < 16; ++kk) d2r[kk] = dW2[(part * 16 + kk) * 16 + c];
    float bbl = b2[lane];
    float bb1 = db1[lane];
    float ob  = db2[c];
    int v0 = blockIdx.x * 4 + wave;
    int stride = gridDim.x * 4;
    for (int v = v0; v < N; v += stride) {
        int start = rowptr[v], cnt = counts[v];
        float dv = dinv[v];
        float acc = dv * Yin[(size_t)v * 64 + lane];
        for (int base = 0; base < cnt; base += 64) {
            int nb = min(64, cnt - base);
            int idx = 0; float ds = 0.f;
            if (lane < nb) {
                idx = csr[start + base + lane];
                ds  = csrw[start + base + lane];
            }
            for (int jj = 0; jj < nb; ++jj) {
                int s = __shfl(idx, jj);
                float d = __shfl(ds, jj);
                acc = fmaf(d, Yin[(size_t)s * 64 + lane], acc);
            }
        }
        float h2 = fmaxf(fmaf(dv, acc, bbl), 0.f);   // relu(agg + b2)
        float a1 = bb1;
#pragma unroll
        for (int k = 0; k < 64; ++k)
            a1 = fmaf(__shfl(h2, k), D1[k * 64 + lane], a1);
        a1 = fmaxf(a1, 0.f);
        float o = 0.f;
#pragma unroll
        for (int kk = 0; kk < 16; ++kk)
            o = fmaf(__shfl(a1, part * 16 + kk), d2r[kk], o);
        o += __shfl_xor(o, 16);
        o += __shfl_xor(o, 32);
        if (lane < 16) out[(size_t)v * 16 + lane] = o + ob;
    }
}

// ---------------- launch ----------------

extern "C" void kernel_launch(void* const* d_in, const int* in_sizes, int n_in,
                              void* d_out, int out_size, void* d_ws, size_t ws_size,
                              hipStream_t stream) {
    const float* x   = (const float*)d_in[0];
    const int*   ei  = (const int*)d_in[1];
    const float* W1  = (const float*)d_in[2];
    const float* b1  = (const float*)d_in[3];
    const float* W2  = (const float*)d_in[4];
    const float* b2  = (const float*)d_in[5];
    const float* dW1 = (const float*)d_in[6];
    const float* db1 = (const float*)d_in[7];
    const float* dW2 = (const float*)d_in[8];
    const float* db2 = (const float*)d_in[9];
    float* out = (float*)d_out;

    int N = in_sizes[0] / 64;
    int E = in_sizes[1] / 2;
    const int* src = ei;
    const int* dst = ei + E;

    size_t off = 0;
    auto alloc = [&](size_t bytes) {
        void* p = (char*)d_ws + off;
        off += (bytes + 511) & ~(size_t)511;
        return p;
    };
    int*   counts = (int*)alloc((size_t)N * 4);
    int*   fillc  = (int*)alloc((size_t)N * 4);
    int*   rowptr = (int*)alloc((size_t)N * 4);
    int*   bsums  = (int*)alloc(512 * 4);
    int*   csr    = (int*)alloc((size_t)E * 4);
    float* csrw   = (float*)alloc((size_t)E * 4);
    float* dinv   = (float*)alloc((size_t)N * 4);
    float* xw     = (float*)alloc((size_t)N * 64 * 4);
    float* yw     = (float*)alloc((size_t)N * 64 * 4);

    hipMemsetAsync(counts, 0, (size_t)N * 4, stream);
    hipMemsetAsync(fillc, 0, (size_t)N * 4, stream);

    int nbN = (N + 255) / 256;
    int nbE = (E + 255) / 256;

    count_kernel<<<nbE, 256, 0, stream>>>(dst, counts, E);
    scan_local<<<nbN, 256, 0, stream>>>(counts, rowptr, bsums, dinv, N);
    scan_bsums<<<1, 512, 0, stream>>>(bsums, nbN);
    scan_add<<<nbN, 256, 0, stream>>>(rowptr, bsums, N);
    fill_kernel<<<nbE, 256, 0, stream>>>(src, dst, rowptr, fillc, dinv, csr, csrw, E);

    gemm64_kernel<<<4096, 128, 0, stream>>>(x, W1, xw, N);
    agg_mm_kernel<<<2048, 256, 0, stream>>>(xw, csr, csrw, rowptr, counts, dinv, b1, W2, yw, N);
    agg_head_kernel<<<2048, 256, 0, stream>>>(yw, csr, csrw, rowptr, counts, dinv, b2,
                                              dW1, db1, dW2, db2, out, N);
}